// Round 4
// baseline (893.027 us; speedup 1.0000x reference)
//
#include <hip/hip_runtime.h>

#define DEVI __device__ __forceinline__

typedef __bf16 bf16x8 __attribute__((ext_vector_type(8)));
typedef float  f32x4  __attribute__((ext_vector_type(4)));
typedef unsigned short ushort8_t __attribute__((ext_vector_type(8)));

constexpr size_t XOUT_ELEMS = (size_t)64 * 512 * 512; // 16,777,216

DEVI unsigned short f2b(float f) {
  __bf16 h = (__bf16)f;               // RNE convert
  return __builtin_bit_cast(unsigned short, h);
}

// ---------------------------------------------------------------------------
// Decode subgraph_sizes (int64 vs int32 layout detection — passed r0/r1)
// ---------------------------------------------------------------------------
__global__ void k_decode(const int* __restrict__ ss, int* __restrict__ ns) {
  int t = threadIdx.x; // 0..63
  int odd = ss[2 * t + 1];
  unsigned long long bal = __ballot(odd == 0);
  bool is64 = (bal == 0xFFFFFFFFFFFFFFFFull);
  if (is64) {
    const long long* s64 = (const long long*)ss;
    ns[2 * t]     = (int)s64[2 * t];
    ns[2 * t + 1] = (int)s64[2 * t + 1];
  } else {
    ns[2 * t]     = ss[2 * t];
    ns[2 * t + 1] = ss[2 * t + 1];
  }
}

// ---------------------------------------------------------------------------
// gt (f32 for g_out) + gth (bf16 A operand for k_gadd)
// ---------------------------------------------------------------------------
__global__ void k_gt(const float* __restrict__ gs, const float* __restrict__ W,
                     const float* __restrict__ bias, float* __restrict__ gt,
                     unsigned short* __restrict__ gth) {
  __shared__ float srow[4][512];
  int r0  = blockIdx.y * 4;
  int col = blockIdx.x * 256 + threadIdx.x;
  for (int i = threadIdx.x; i < 4 * 512; i += 256)
    srow[i >> 9][i & 511] = gs[(size_t)r0 * 512 + i];
  __syncthreads();
  float acc[4] = {0.f, 0.f, 0.f, 0.f};
  for (int g = 0; g < 512; ++g) {
    float w = W[(size_t)g * 512 + col];
    acc[0] += srow[0][g] * w;
    acc[1] += srow[1][g] * w;
    acc[2] += srow[2][g] * w;
    acc[3] += srow[3][g] * w;
  }
  float bb = bias[col];
  #pragma unroll
  for (int r = 0; r < 4; ++r) {
    float v = acc[r] + bb;
    gt [(size_t)(r0 + r) * 512 + col] = v;
    gth[(size_t)(r0 + r) * 512 + col] = f2b(v);
  }
}

// ---------------------------------------------------------------------------
// g_out = relu(BN(gt)) -> d_out tail  (fp32-exact)
// ---------------------------------------------------------------------------
__global__ void k_gbn(const float* __restrict__ gt, const float* __restrict__ gamma,
                      const float* __restrict__ beta, float* __restrict__ gout) {
  int col = blockIdx.x * 64 + threadIdx.x;
  float s = 0.f, q = 0.f;
  for (int r = 0; r < 128; ++r) {
    float v = gt[(size_t)r * 512 + col];
    s += v; q += v * v;
  }
  float m   = s * (1.f / 128.f);
  float var = q * (1.f / 128.f) - m * m;
  float inv = 1.f / sqrtf(var + 1e-5f);
  float g = gamma[col], b = beta[col];
  for (int r = 0; r < 128; ++r) {
    float v = (gt[(size_t)r * 512 + col] - m) * inv * g + b;
    gout[(size_t)r * 512 + col] = fmaxf(v, 0.f);
  }
}

// ---------------------------------------------------------------------------
// f32 -> bf16 bulk convert
// ---------------------------------------------------------------------------
__global__ void k_cvt(const float* __restrict__ in, unsigned short* __restrict__ out,
                      long n8) {
  long i = (long)blockIdx.x * blockDim.x + threadIdx.x;
  long stride = (long)gridDim.x * blockDim.x;
  for (; i < n8; i += stride) {
    float4 a = ((const float4*)in)[2 * i];
    float4 b = ((const float4*)in)[2 * i + 1];
    ushort8_t o;
    o[0] = f2b(a.x); o[1] = f2b(a.y); o[2] = f2b(a.z); o[3] = f2b(a.w);
    o[4] = f2b(b.x); o[5] = f2b(b.y); o[6] = f2b(b.z); o[7] = f2b(b.w);
    *(ushort8_t*)&out[i * 8] = o;
  }
}

// ---------------------------------------------------------------------------
// W_gc [e][k=1024][o=512] f32  ->  wT [e][o=512][k=1024] bf16
// ---------------------------------------------------------------------------
__global__ void k_cvt_w(const float* __restrict__ W, unsigned short* __restrict__ wT) {
  __shared__ float t[32][33];
  int k0 = blockIdx.x * 32, o0 = blockIdx.y * 32, e = blockIdx.z;
  const float* Wb = W + (size_t)e * 1024 * 512;
  unsigned short* Tb = wT + (size_t)e * 512 * 1024;
  int tid = threadIdx.x;
  #pragma unroll
  for (int p = 0; p < 4; ++p) {
    int kl = p * 8 + (tid >> 5), ol = tid & 31;
    t[kl][ol] = Wb[(size_t)(k0 + kl) * 512 + o0 + ol];
  }
  __syncthreads();
  #pragma unroll
  for (int p = 0; p < 4; ++p) {
    int ol = p * 8 + (tid >> 5), kl = tid & 31;
    Tb[(size_t)(o0 + ol) * 1024 + k0 + kl] = f2b(t[kl][ol]);
  }
}

// ---------------------------------------------------------------------------
// MFMA GEMM core (m97 structure, verified r2): 128x128 C tile, 4 waves, BK=32.
// ---------------------------------------------------------------------------
DEVI void gl_lds16(const unsigned short* g, unsigned short* l) {
  __builtin_amdgcn_global_load_lds(
      (const __attribute__((address_space(1))) void*)g,
      (__attribute__((address_space(3))) void*)l, 16, 0, 0);
}

DEVI int lds_idx(int row, int slot) {  // ushort index of a 16B slot
  return row * 32 + ((slot ^ ((row >> 1) & 3)) << 3);
}

template <class FA, class FB>
DEVI void mfma_core(unsigned short* As, unsigned short* Bs, FA srcA, FB srcB,
                    int NT, f32x4 (&acc)[4][4]) {
  const int tid  = threadIdx.x;
  const int lane = tid & 63;
  const int wave = tid >> 6;
  const int wr = wave >> 1, wc = wave & 1;
  const int fr = lane & 15, fs = lane >> 4;

  const int c0 = tid,       r0 = c0 >> 2, s0 = (c0 & 3) ^ ((r0 >> 1) & 3);
  const int c1 = tid + 256, r1 = c1 >> 2, s1 = (c1 & 3) ^ ((r1 >> 1) & 3);

  int aoff[4], boff[4];
  #pragma unroll
  for (int i = 0; i < 4; ++i) {
    aoff[i] = lds_idx(wr * 64 + i * 16 + fr, fs);
    boff[i] = lds_idx(wc * 64 + i * 16 + fr, fs);
  }

  gl_lds16(srcA(r0, s0 * 8, 0), As + c0 * 8);
  gl_lds16(srcA(r1, s1 * 8, 0), As + c1 * 8);
  gl_lds16(srcB(r0, s0 * 8, 0), Bs + c0 * 8);
  gl_lds16(srcB(r1, s1 * 8, 0), Bs + c1 * 8);

  for (int kt = 0; kt < NT; ++kt) {
    __syncthreads();                       // staging of kt visible
    bf16x8 af[4], bf[4];
    #pragma unroll
    for (int i = 0; i < 4; ++i) af[i] = *(const bf16x8*)(As + aoff[i]);
    #pragma unroll
    for (int j = 0; j < 4; ++j) bf[j] = *(const bf16x8*)(Bs + boff[j]);
    if (kt + 1 < NT) {
      __syncthreads();                     // all waves done reading
      gl_lds16(srcA(r0, s0 * 8, kt + 1), As + c0 * 8);
      gl_lds16(srcA(r1, s1 * 8, kt + 1), As + c1 * 8);
      gl_lds16(srcB(r0, s0 * 8, kt + 1), Bs + c0 * 8);
      gl_lds16(srcB(r1, s1 * 8, kt + 1), Bs + c1 * 8);
    }
    #pragma unroll
    for (int i = 0; i < 4; ++i)
      #pragma unroll
      for (int j = 0; j < 4; ++j)
        acc[i][j] = __builtin_amdgcn_mfma_f32_16x16x32_bf16(af[i], bf[j], acc[i][j], 0, 0, 0);
  }
}

// ---------------------------------------------------------------------------
// k_gadd: gadd[m=2b+k][o'=e*512+o] = gth[m] . W_gc[e][512+..][o]  (f32 out)
// M=128, N=2048, K=512 -> 16 blocks of 128x128.
// ---------------------------------------------------------------------------
__global__ __launch_bounds__(256) void k_gadd(
    const unsigned short* __restrict__ gth, const unsigned short* __restrict__ wT,
    float* __restrict__ gadd) {
  __shared__ __align__(16) unsigned short As[4096], Bs[4096];
  const int otile = blockIdx.x * 128;

  auto srcA = [=](int row, int kofs, int kt) -> const unsigned short* {
    return gth + (size_t)row * 512 + kt * 32 + kofs;
  };
  auto srcB = [=](int row, int kofs, int kt) -> const unsigned short* {
    int op = otile + row;
    int e = op >> 9, o = op & 511;
    return wT + (size_t)e * 524288 + (size_t)o * 1024 + 512 + kt * 32 + kofs;
  };

  f32x4 acc[4][4];
  #pragma unroll
  for (int i = 0; i < 4; ++i)
    #pragma unroll
    for (int j = 0; j < 4; ++j) acc[i][j] = (f32x4){0.f, 0.f, 0.f, 0.f};

  mfma_core(As, Bs, srcA, srcB, 16, acc);

  const int lane = threadIdx.x & 63, wave = threadIdx.x >> 6;
  const int wr = wave >> 1, wc = wave & 1, fr = lane & 15, fs = lane >> 4;
  #pragma unroll
  for (int i = 0; i < 4; ++i) {
    int m = wr * 64 + i * 16 + fs * 4;
    #pragma unroll
    for (int j = 0; j < 4; ++j) {
      int op = otile + wc * 64 + j * 16 + fr;
      #pragma unroll
      for (int r = 0; r < 4; ++r)
        gadd[(size_t)(m + r) * 2048 + op] = acc[i][j][r];
    }
  }
}

// ---------------------------------------------------------------------------
// GEMM1 (K=512 now): support^T[gi*4+e][o][m] = (x[b] @ Wx[e])^T + gadd-select
// 1D grid 16*4*gc, zi fastest -> XCD = b%8 when gc=16.
// ---------------------------------------------------------------------------
__global__ __launch_bounds__(256) void k_support(
    const unsigned short* __restrict__ xh, const unsigned short* __restrict__ wT,
    const float* __restrict__ gadd, const int* __restrict__ ns,
    unsigned short* __restrict__ supT, int b0, int gc) {
  __shared__ __align__(16) unsigned short As[4096], Bs[4096];
  int flat = blockIdx.x;
  const int zi = flat % gc; flat /= gc;
  const int e  = flat & 3;  flat >>= 2;
  const int otile = (flat & 3) * 128;
  const int row0  = (flat >> 2) * 128;
  const int b  = b0 + zi;
  const int n1  = ns[2 * b];
  const int n12 = n1 + ns[2 * b + 1];
  const unsigned short* xb = xh + (size_t)b * 262144;
  const unsigned short* wb = wT + (size_t)e * 524288;

  auto srcA = [=](int row, int kofs, int kt) -> const unsigned short* {
    return xb + (size_t)(row0 + row) * 512 + kt * 32 + kofs;
  };
  auto srcB = [=](int row, int kofs, int kt) -> const unsigned short* {
    return wb + (size_t)(otile + row) * 1024 + kt * 32 + kofs;
  };

  f32x4 acc[4][4];
  #pragma unroll
  for (int i = 0; i < 4; ++i)
    #pragma unroll
    for (int j = 0; j < 4; ++j) acc[i][j] = (f32x4){0.f, 0.f, 0.f, 0.f};

  mfma_core(As, Bs, srcA, srcB, 16, acc);

  const int lane = threadIdx.x & 63, wave = threadIdx.x >> 6;
  const int wr = wave >> 1, wc = wave & 1, fr = lane & 15, fs = lane >> 4;
  unsigned short* sp = supT + (size_t)(zi * 4 + e) * 262144;
  #pragma unroll
  for (int j = 0; j < 4; ++j) {
    int o = otile + wc * 64 + j * 16 + fr;
    float g0 = gadd[(size_t)(2 * b)     * 2048 + e * 512 + o];
    float g1 = gadd[(size_t)(2 * b + 1) * 2048 + e * 512 + o];
    #pragma unroll
    for (int i = 0; i < 4; ++i) {
      int m = row0 + wr * 64 + i * 16 + fs * 4;
      ushort4 h;
      #pragma unroll
      for (int r = 0; r < 4; ++r) {
        int mr = m + r;
        float add = (mr < n1) ? g0 : ((mr < n12) ? g1 : 0.f);
        ((unsigned short*)&h)[r] = f2b(acc[i][j][r] + add);
      }
      *(ushort4*)&sp[(size_t)o * 512 + m] = h;
    }
  }
}

// ---------------------------------------------------------------------------
// GEMM2: out[b][n][o] = sum_{e,m} adj[b,e][n][m] * supT[e][o][m] + b_gc
// 1D grid 16*gc, zi fastest -> XCD = b%8 when gc=16.
// ---------------------------------------------------------------------------
__global__ __launch_bounds__(256) void k_xout(
    const unsigned short* __restrict__ adjh, const unsigned short* __restrict__ supT,
    const float* __restrict__ bgc, float* __restrict__ out,
    float* __restrict__ gsum, float* __restrict__ gsq, int b0, int gc) {
  __shared__ __align__(16) unsigned short As[4096], Bs[4096];
  int flat = blockIdx.x;
  const int zi = flat % gc; flat /= gc;
  const int otile = (flat & 3) * 128;
  const int row0  = (flat >> 2) * 128;
  const int b  = b0 + zi;
  const unsigned short* ab = adjh + (size_t)b * 4 * 262144;
  const unsigned short* sb = supT + (size_t)zi * 4 * 262144;

  auto srcA = [=](int row, int kofs, int kt) -> const unsigned short* {
    int k = kt * 32 + kofs;
    int e = k >> 9, m = k & 511;
    return ab + ((size_t)e * 512 + row0 + row) * 512 + m;
  };
  auto srcB = [=](int row, int kofs, int kt) -> const unsigned short* {
    int k = kt * 32 + kofs;
    int e = k >> 9, m = k & 511;
    return sb + ((size_t)e * 512 + otile + row) * 512 + m;
  };

  f32x4 acc[4][4];
  #pragma unroll
  for (int i = 0; i < 4; ++i)
    #pragma unroll
    for (int j = 0; j < 4; ++j) acc[i][j] = (f32x4){0.f, 0.f, 0.f, 0.f};

  mfma_core(As, Bs, srcA, srcB, 64, acc);

  const int tid = threadIdx.x;
  const int lane = tid & 63, wave = tid >> 6;
  const int wr = wave >> 1, wc = wave & 1, fr = lane & 15, fs = lane >> 4;

  float cs[4], cq[4];
  #pragma unroll
  for (int j = 0; j < 4; ++j) {
    int o = otile + wc * 64 + j * 16 + fr;
    float bb = bgc[o];
    float s = 0.f, q = 0.f;
    #pragma unroll
    for (int i = 0; i < 4; ++i) {
      int nb = row0 + wr * 64 + i * 16 + fs * 4;
      #pragma unroll
      for (int r = 0; r < 4; ++r) {
        float v = acc[i][j][r] + bb;
        out[((size_t)b * 512 + nb + r) * 512 + o] = v;
        s += v; q += v * v;
      }
    }
    cs[j] = s; cq[j] = q;
  }

  __syncthreads();
  float* red = (float*)As;   // reuse LDS
  red[tid] = 0.f;
  __syncthreads();
  #pragma unroll
  for (int j = 0; j < 4; ++j) {
    int cl = wc * 64 + j * 16 + fr;
    atomicAdd(&red[cl], cs[j]);
    atomicAdd(&red[128 + cl], cq[j]);
  }
  __syncthreads();
  if (tid < 128) {
    atomicAdd(&gsum[otile + tid], red[tid]);
    atomicAdd(&gsq[otile + tid],  red[128 + tid]);
  }
}

// ---------------------------------------------------------------------------
// In-place BN + mask + relu
// ---------------------------------------------------------------------------
__global__ void k_norm(const float* __restrict__ gsum, const float* __restrict__ gsq,
                       const float* __restrict__ gamma, const float* __restrict__ beta,
                       const float* __restrict__ mask, float* __restrict__ out) {
  __shared__ float sc[512], sh[512];
  for (int c = threadIdx.x; c < 512; c += blockDim.x) {
    float m   = gsum[c] * (1.f / 32768.f);
    float var = gsq[c] * (1.f / 32768.f) - m * m;
    float inv = 1.f / sqrtf(var + 1e-5f);
    float g = gamma[c] * inv;
    sc[c] = g;
    sh[c] = beta[c] - m * g;
  }
  __syncthreads();
  size_t i0 = (size_t)blockIdx.x * blockDim.x + threadIdx.x;
  size_t stride = (size_t)gridDim.x * blockDim.x;
  size_t n4 = XOUT_ELEMS / 4;
  for (size_t i = i0; i < n4; i += stride) {
    float4 p = ((const float4*)out)[i];
    int c = (int)((i * 4) & 511);
    size_t row = (i * 4) >> 9;
    float mk = mask[row];
    p.x = fmaxf((p.x * sc[c + 0] + sh[c + 0]) * mk, 0.f);
    p.y = fmaxf((p.y * sc[c + 1] + sh[c + 1]) * mk, 0.f);
    p.z = fmaxf((p.z * sc[c + 2] + sh[c + 2]) * mk, 0.f);
    p.w = fmaxf((p.w * sc[c + 3] + sh[c + 3]) * mk, 0.f);
    ((float4*)out)[i] = p;
  }
}

// ---------------------------------------------------------------------------
extern "C" void kernel_launch(void* const* d_in, const int* in_sizes, int n_in,
                              void* d_out, int out_size, void* d_ws, size_t ws_size,
                              hipStream_t stream) {
  const float* x    = (const float*)d_in[0];
  const float* adj  = (const float*)d_in[1];
  const float* gs   = (const float*)d_in[2];
  const int*   ssz  = (const int*)d_in[3];
  const float* mask = (const float*)d_in[4];
  const float* Wgfc = (const float*)d_in[5];
  const float* bgfc = (const float*)d_in[6];
  const float* Wgc  = (const float*)d_in[7];
  const float* bgc  = (const float*)d_in[8];
  const float* gn   = (const float*)d_in[9];
  const float* btn  = (const float*)d_in[10];
  const float* gg   = (const float*)d_in[11];
  const float* btg  = (const float*)d_in[12];
  float* out = (float*)d_out;

  // workspace layout (ws >= ~200 MiB assumed; adaptive G guards smaller)
  char* w = (char*)d_ws;
  float*          gt   = (float*)w;                               // 256 KiB
  unsigned short* gth  = (unsigned short*)(w + 262144);           // 128 KiB
  float*          gadd = (float*)(w + 393216);                    // 1 MiB
  int*            ns   = (int*)(w + 1441792);                     // 512 B
  float*          gsum = (float*)(w + 1442304);                   // 2 KiB
  float*          gsq  = (float*)(w + 1444352);                   // 2 KiB
  unsigned short* xh   = (unsigned short*)(w + ((size_t)2  << 20));  // 32 MiB
  unsigned short* wT   = (unsigned short*)(w + ((size_t)34 << 20));  // 4 MiB
  unsigned short* adjh = (unsigned short*)(w + ((size_t)40 << 20));  // 128 MiB
  unsigned short* supT = (unsigned short*)(w + ((size_t)168 << 20)); // 2 MiB/b chunk

  long long avail = (long long)ws_size - (168ll << 20);
  int G = (avail > 0) ? (int)(avail / (2ll << 20)) : 0;
  if (G < 1) G = 1;
  if (G > 16) G = 16;

  k_decode<<<1, 64, 0, stream>>>(ssz, ns);
  k_gt<<<dim3(2, 32), 256, 0, stream>>>(gs, Wgfc, bgfc, gt, gth);
  k_gbn<<<8, 64, 0, stream>>>(gt, gg, btg, out + XOUT_ELEMS);
  hipMemsetAsync(gsum, 0, 4096, stream);

  k_cvt<<<2048, 256, 0, stream>>>(x, xh, (long)(16777216 / 8));
  k_cvt<<<4096, 256, 0, stream>>>(adj, adjh, (long)(67108864 / 8));
  k_cvt_w<<<dim3(32, 16, 4), 256, 0, stream>>>(Wgc, wT);
  k_gadd<<<16, 256, 0, stream>>>(gth, wT, gadd);

  for (int b0 = 0; b0 < 64; b0 += G) {
    int gc = 64 - b0; if (gc > G) gc = G;
    k_support<<<16 * 4 * gc, 256, 0, stream>>>(xh, wT, gadd, ns, supT, b0, gc);
    k_xout<<<16 * gc, 256, 0, stream>>>(adjh, supT, bgc, out, gsum, gsq, b0, gc);
  }

  k_norm<<<2048, 256, 0, stream>>>(gsum, gsq, gn, btn, mask, out);
}

// Round 6
// 819.445 us; speedup vs baseline: 1.0898x; 1.0898x over previous
//
#include <hip/hip_runtime.h>

#define DEVI __device__ __forceinline__

typedef __bf16 bf16x8 __attribute__((ext_vector_type(8)));
typedef float  f32x4  __attribute__((ext_vector_type(4)));
typedef unsigned short ushort8_t __attribute__((ext_vector_type(8)));

constexpr size_t XOUT_ELEMS = (size_t)64 * 512 * 512; // 16,777,216

DEVI unsigned short f2b(float f) {
  __bf16 h = (__bf16)f;               // RNE convert
  return __builtin_bit_cast(unsigned short, h);
}

// ---------------------------------------------------------------------------
// Decode subgraph_sizes (int64 vs int32 layout detection — passed r0-r4)
// ---------------------------------------------------------------------------
__global__ void k_decode(const int* __restrict__ ss, int* __restrict__ ns) {
  int t = threadIdx.x; // 0..63
  int odd = ss[2 * t + 1];
  unsigned long long bal = __ballot(odd == 0);
  bool is64 = (bal == 0xFFFFFFFFFFFFFFFFull);
  if (is64) {
    const long long* s64 = (const long long*)ss;
    ns[2 * t]     = (int)s64[2 * t];
    ns[2 * t + 1] = (int)s64[2 * t + 1];
  } else {
    ns[2 * t]     = ss[2 * t];
    ns[2 * t + 1] = ss[2 * t + 1];
  }
}

// ---------------------------------------------------------------------------
// gt (f32 for g_out) + gth (bf16 A operand for k_gadd)
// ---------------------------------------------------------------------------
__global__ void k_gt(const float* __restrict__ gs, const float* __restrict__ W,
                     const float* __restrict__ bias, float* __restrict__ gt,
                     unsigned short* __restrict__ gth) {
  __shared__ float srow[4][512];
  int r0  = blockIdx.y * 4;
  int col = blockIdx.x * 256 + threadIdx.x;
  for (int i = threadIdx.x; i < 4 * 512; i += 256)
    srow[i >> 9][i & 511] = gs[(size_t)r0 * 512 + i];
  __syncthreads();
  float acc[4] = {0.f, 0.f, 0.f, 0.f};
  for (int g = 0; g < 512; ++g) {
    float w = W[(size_t)g * 512 + col];
    acc[0] += srow[0][g] * w;
    acc[1] += srow[1][g] * w;
    acc[2] += srow[2][g] * w;
    acc[3] += srow[3][g] * w;
  }
  float bb = bias[col];
  #pragma unroll
  for (int r = 0; r < 4; ++r) {
    float v = acc[r] + bb;
    gt [(size_t)(r0 + r) * 512 + col] = v;
    gth[(size_t)(r0 + r) * 512 + col] = f2b(v);
  }
}

// ---------------------------------------------------------------------------
// g_out = relu(BN(gt)) -> d_out tail  (fp32-exact)
// ---------------------------------------------------------------------------
__global__ void k_gbn(const float* __restrict__ gt, const float* __restrict__ gamma,
                      const float* __restrict__ beta, float* __restrict__ gout) {
  int col = blockIdx.x * 64 + threadIdx.x;
  float s = 0.f, q = 0.f;
  for (int r = 0; r < 128; ++r) {
    float v = gt[(size_t)r * 512 + col];
    s += v; q += v * v;
  }
  float m   = s * (1.f / 128.f);
  float var = q * (1.f / 128.f) - m * m;
  float inv = 1.f / sqrtf(var + 1e-5f);
  float g = gamma[col], b = beta[col];
  for (int r = 0; r < 128; ++r) {
    float v = (gt[(size_t)r * 512 + col] - m) * inv * g + b;
    gout[(size_t)r * 512 + col] = fmaxf(v, 0.f);
  }
}

// ---------------------------------------------------------------------------
// f32 -> bf16 bulk convert
// ---------------------------------------------------------------------------
__global__ void k_cvt(const float* __restrict__ in, unsigned short* __restrict__ out,
                      long n8) {
  long i = (long)blockIdx.x * blockDim.x + threadIdx.x;
  long stride = (long)gridDim.x * blockDim.x;
  for (; i < n8; i += stride) {
    float4 a = ((const float4*)in)[2 * i];
    float4 b = ((const float4*)in)[2 * i + 1];
    ushort8_t o;
    o[0] = f2b(a.x); o[1] = f2b(a.y); o[2] = f2b(a.z); o[3] = f2b(a.w);
    o[4] = f2b(b.x); o[5] = f2b(b.y); o[6] = f2b(b.z); o[7] = f2b(b.w);
    *(ushort8_t*)&out[i * 8] = o;
  }
}

// ---------------------------------------------------------------------------
// W_gc [e][k=1024][o=512] f32  ->  wT [e][o=512][k=1024] bf16
// ---------------------------------------------------------------------------
__global__ void k_cvt_w(const float* __restrict__ W, unsigned short* __restrict__ wT) {
  __shared__ float t[32][33];
  int k0 = blockIdx.x * 32, o0 = blockIdx.y * 32, e = blockIdx.z;
  const float* Wb = W + (size_t)e * 1024 * 512;
  unsigned short* Tb = wT + (size_t)e * 512 * 1024;
  int tid = threadIdx.x;
  #pragma unroll
  for (int p = 0; p < 4; ++p) {
    int kl = p * 8 + (tid >> 5), ol = tid & 31;
    t[kl][ol] = Wb[(size_t)(k0 + kl) * 512 + o0 + ol];
  }
  __syncthreads();
  #pragma unroll
  for (int p = 0; p < 4; ++p) {
    int ol = p * 8 + (tid >> 5), kl = tid & 31;
    Tb[(size_t)(o0 + ol) * 1024 + k0 + kl] = f2b(t[kl][ol]);
  }
}

// ---------------------------------------------------------------------------
// MFMA GEMM core (m97 structure, verified r2): 128x128 C tile, 4 waves, BK=32.
// ---------------------------------------------------------------------------
DEVI void gl_lds16(const unsigned short* g, unsigned short* l) {
  __builtin_amdgcn_global_load_lds(
      (const __attribute__((address_space(1))) void*)g,
      (__attribute__((address_space(3))) void*)l, 16, 0, 0);
}

DEVI int lds_idx(int row, int slot) {  // ushort index of a 16B slot
  return row * 32 + ((slot ^ ((row >> 1) & 3)) << 3);
}

template <class FA, class FB>
DEVI void mfma_core(unsigned short* As, unsigned short* Bs, FA srcA, FB srcB,
                    int NT, f32x4 (&acc)[4][4]) {
  const int tid  = threadIdx.x;
  const int lane = tid & 63;
  const int wave = tid >> 6;
  const int wr = wave >> 1, wc = wave & 1;
  const int fr = lane & 15, fs = lane >> 4;

  const int c0 = tid,       r0 = c0 >> 2, s0 = (c0 & 3) ^ ((r0 >> 1) & 3);
  const int c1 = tid + 256, r1 = c1 >> 2, s1 = (c1 & 3) ^ ((r1 >> 1) & 3);

  int aoff[4], boff[4];
  #pragma unroll
  for (int i = 0; i < 4; ++i) {
    aoff[i] = lds_idx(wr * 64 + i * 16 + fr, fs);
    boff[i] = lds_idx(wc * 64 + i * 16 + fr, fs);
  }

  gl_lds16(srcA(r0, s0 * 8, 0), As + c0 * 8);
  gl_lds16(srcA(r1, s1 * 8, 0), As + c1 * 8);
  gl_lds16(srcB(r0, s0 * 8, 0), Bs + c0 * 8);
  gl_lds16(srcB(r1, s1 * 8, 0), Bs + c1 * 8);

  for (int kt = 0; kt < NT; ++kt) {
    __syncthreads();                       // staging of kt visible
    bf16x8 af[4], bf[4];
    #pragma unroll
    for (int i = 0; i < 4; ++i) af[i] = *(const bf16x8*)(As + aoff[i]);
    #pragma unroll
    for (int j = 0; j < 4; ++j) bf[j] = *(const bf16x8*)(Bs + boff[j]);
    if (kt + 1 < NT) {
      __syncthreads();                     // all waves done reading
      gl_lds16(srcA(r0, s0 * 8, kt + 1), As + c0 * 8);
      gl_lds16(srcA(r1, s1 * 8, kt + 1), As + c1 * 8);
      gl_lds16(srcB(r0, s0 * 8, kt + 1), Bs + c0 * 8);
      gl_lds16(srcB(r1, s1 * 8, kt + 1), Bs + c1 * 8);
    }
    #pragma unroll
    for (int i = 0; i < 4; ++i)
      #pragma unroll
      for (int j = 0; j < 4; ++j)
        acc[i][j] = __builtin_amdgcn_mfma_f32_16x16x32_bf16(af[i], bf[j], acc[i][j], 0, 0, 0);
  }
}

// ---------------------------------------------------------------------------
// k_gadd: gadd[m=2b+k][o'=e*512+o] = gth[m] . W_gc[e][512+..][o]  (f32 out)
// ---------------------------------------------------------------------------
__global__ __launch_bounds__(256) void k_gadd(
    const unsigned short* __restrict__ gth, const unsigned short* __restrict__ wT,
    float* __restrict__ gadd) {
  __shared__ __align__(16) unsigned short As[4096], Bs[4096];
  const int otile = blockIdx.x * 128;

  auto srcA = [=](int row, int kofs, int kt) -> const unsigned short* {
    return gth + (size_t)row * 512 + kt * 32 + kofs;
  };
  auto srcB = [=](int row, int kofs, int kt) -> const unsigned short* {
    int op = otile + row;
    int e = op >> 9, o = op & 511;
    return wT + (size_t)e * 524288 + (size_t)o * 1024 + 512 + kt * 32 + kofs;
  };

  f32x4 acc[4][4];
  #pragma unroll
  for (int i = 0; i < 4; ++i)
    #pragma unroll
    for (int j = 0; j < 4; ++j) acc[i][j] = (f32x4){0.f, 0.f, 0.f, 0.f};

  mfma_core(As, Bs, srcA, srcB, 16, acc);

  const int lane = threadIdx.x & 63, wave = threadIdx.x >> 6;
  const int wr = wave >> 1, wc = wave & 1, fr = lane & 15, fs = lane >> 4;
  #pragma unroll
  for (int i = 0; i < 4; ++i) {
    int m = wr * 64 + i * 16 + fs * 4;
    #pragma unroll
    for (int j = 0; j < 4; ++j) {
      int op = otile + wc * 64 + j * 16 + fr;
      #pragma unroll
      for (int r = 0; r < 4; ++r)
        gadd[(size_t)(m + r) * 2048 + op] = acc[i][j][r];
    }
  }
}

// ---------------------------------------------------------------------------
// GEMM1 (K=512): support^T[zi*4+e][o][m] = (x[b] @ Wx[e])^T + gadd-select
// XCD-pinned mapping (gc%8==0): xcd = bid&7, batch = bgrp*8+xcd — all 64
// tiles of a batch co-resident on one XCD; wT k<512 footprint (2 MB) +
// xh[b] (0.5 MB) fit its 4 MB L2.
// ---------------------------------------------------------------------------
__global__ __launch_bounds__(256) void k_support(
    const unsigned short* __restrict__ xh, const unsigned short* __restrict__ wT,
    const float* __restrict__ gadd, const int* __restrict__ ns,
    unsigned short* __restrict__ supT, int b0, int gc) {
  __shared__ __align__(16) unsigned short As[4096], Bs[4096];
  int flat = blockIdx.x;
  int zi, e, otile, row0;
  if ((gc & 7) == 0) {
    int xcd = flat & 7;
    int j = flat >> 3;              // [0, 8*gc)
    int bgrp = j >> 6;              // [0, gc/8)
    int tile = j & 63;
    zi = bgrp * 8 + xcd;
    e = tile & 3;
    otile = ((tile >> 2) & 3) * 128;
    row0  = (tile >> 4) * 128;
  } else {
    zi = flat % gc; flat /= gc;
    e  = flat & 3;  flat >>= 2;
    otile = (flat & 3) * 128;
    row0  = (flat >> 2) * 128;
  }
  const int b  = b0 + zi;
  const int n1  = ns[2 * b];
  const int n12 = n1 + ns[2 * b + 1];
  const unsigned short* xb = xh + (size_t)b * 262144;
  const unsigned short* wb = wT + (size_t)e * 524288;

  auto srcA = [=](int row, int kofs, int kt) -> const unsigned short* {
    return xb + (size_t)(row0 + row) * 512 + kt * 32 + kofs;
  };
  auto srcB = [=](int row, int kofs, int kt) -> const unsigned short* {
    return wb + (size_t)(otile + row) * 1024 + kt * 32 + kofs;
  };

  f32x4 acc[4][4];
  #pragma unroll
  for (int i = 0; i < 4; ++i)
    #pragma unroll
    for (int j = 0; j < 4; ++j) acc[i][j] = (f32x4){0.f, 0.f, 0.f, 0.f};

  mfma_core(As, Bs, srcA, srcB, 16, acc);

  const int lane = threadIdx.x & 63, wave = threadIdx.x >> 6;
  const int wr = wave >> 1, wc = wave & 1, fr = lane & 15, fs = lane >> 4;
  unsigned short* sp = supT + (size_t)(zi * 4 + e) * 262144;
  #pragma unroll
  for (int j = 0; j < 4; ++j) {
    int o = otile + wc * 64 + j * 16 + fr;
    float g0 = gadd[(size_t)(2 * b)     * 2048 + e * 512 + o];
    float g1 = gadd[(size_t)(2 * b + 1) * 2048 + e * 512 + o];
    #pragma unroll
    for (int i = 0; i < 4; ++i) {
      int m = row0 + wr * 64 + i * 16 + fs * 4;
      ushort4 h;
      #pragma unroll
      for (int r = 0; r < 4; ++r) {
        int mr = m + r;
        float add = (mr < n1) ? g0 : ((mr < n12) ? g1 : 0.f);
        ((unsigned short*)&h)[r] = f2b(acc[i][j][r] + add);
      }
      *(ushort4*)&sp[(size_t)o * 512 + m] = h;
    }
  }
}

// ---------------------------------------------------------------------------
// GEMM2: out[b][n][o] = sum_{e,m} adj[b,e][n][m] * supT[e][o][m] + b_gc
// XCD-pinned mapping: 16 tiles of batch b on XCD b%8; adjh[b]+supT[b] = 4 MB
// working set fits that XCD's L2 -> panel re-reads become L2 hits.
// ---------------------------------------------------------------------------
__global__ __launch_bounds__(256) void k_xout(
    const unsigned short* __restrict__ adjh, const unsigned short* __restrict__ supT,
    const float* __restrict__ bgc, float* __restrict__ out,
    float* __restrict__ gsum, float* __restrict__ gsq, int b0, int gc) {
  __shared__ __align__(16) unsigned short As[4096], Bs[4096];
  int flat = blockIdx.x;
  int zi, otile, row0;
  if ((gc & 7) == 0) {
    int xcd = flat & 7;
    int j = flat >> 3;              // [0, 2*gc)
    int bgrp = j >> 4;              // [0, gc/8)
    int tile = j & 15;
    zi = bgrp * 8 + xcd;
    otile = (tile & 3) * 128;
    row0  = (tile >> 2) * 128;
  } else {
    zi = flat % gc; flat /= gc;
    otile = (flat & 3) * 128;
    row0  = (flat >> 2) * 128;
  }
  const int b  = b0 + zi;
  const unsigned short* ab = adjh + (size_t)b * 4 * 262144;
  const unsigned short* sb = supT + (size_t)zi * 4 * 262144;

  auto srcA = [=](int row, int kofs, int kt) -> const unsigned short* {
    int k = kt * 32 + kofs;
    int e = k >> 9, m = k & 511;
    return ab + ((size_t)e * 512 + row0 + row) * 512 + m;
  };
  auto srcB = [=](int row, int kofs, int kt) -> const unsigned short* {
    int k = kt * 32 + kofs;
    int e = k >> 9, m = k & 511;
    return sb + ((size_t)e * 512 + otile + row) * 512 + m;
  };

  f32x4 acc[4][4];
  #pragma unroll
  for (int i = 0; i < 4; ++i)
    #pragma unroll
    for (int j = 0; j < 4; ++j) acc[i][j] = (f32x4){0.f, 0.f, 0.f, 0.f};

  mfma_core(As, Bs, srcA, srcB, 64, acc);

  const int tid = threadIdx.x;
  const int lane = tid & 63, wave = tid >> 6;
  const int wr = wave >> 1, wc = wave & 1, fr = lane & 15, fs = lane >> 4;

  float cs[4], cq[4];
  #pragma unroll
  for (int j = 0; j < 4; ++j) {
    int o = otile + wc * 64 + j * 16 + fr;
    float bb = bgc[o];
    float s = 0.f, q = 0.f;
    #pragma unroll
    for (int i = 0; i < 4; ++i) {
      int nb = row0 + wr * 64 + i * 16 + fs * 4;
      #pragma unroll
      for (int r = 0; r < 4; ++r) {
        float v = acc[i][j][r] + bb;
        out[((size_t)b * 512 + nb + r) * 512 + o] = v;
        s += v; q += v * v;
      }
    }
    cs[j] = s; cq[j] = q;
  }

  __syncthreads();
  float* red = (float*)As;   // reuse LDS
  red[tid] = 0.f;
  __syncthreads();
  #pragma unroll
  for (int j = 0; j < 4; ++j) {
    int cl = wc * 64 + j * 16 + fr;
    atomicAdd(&red[cl], cs[j]);
    atomicAdd(&red[128 + cl], cq[j]);
  }
  __syncthreads();
  if (tid < 128) {
    atomicAdd(&gsum[otile + tid], red[tid]);
    atomicAdd(&gsq[otile + tid],  red[128 + tid]);
  }
}

// ---------------------------------------------------------------------------
// In-place BN + mask + relu
// ---------------------------------------------------------------------------
__global__ void k_norm(const float* __restrict__ gsum, const float* __restrict__ gsq,
                       const float* __restrict__ gamma, const float* __restrict__ beta,
                       const float* __restrict__ mask, float* __restrict__ out) {
  __shared__ float sc[512], sh[512];
  for (int c = threadIdx.x; c < 512; c += blockDim.x) {
    float m   = gsum[c] * (1.f / 32768.f);
    float var = gsq[c] * (1.f / 32768.f) - m * m;
    float inv = 1.f / sqrtf(var + 1e-5f);
    float g = gamma[c] * inv;
    sc[c] = g;
    sh[c] = beta[c] - m * g;
  }
  __syncthreads();
  size_t i0 = (size_t)blockIdx.x * blockDim.x + threadIdx.x;
  size_t stride = (size_t)gridDim.x * blockDim.x;
  size_t n4 = XOUT_ELEMS / 4;
  for (size_t i = i0; i < n4; i += stride) {
    float4 p = ((const float4*)out)[i];
    int c = (int)((i * 4) & 511);
    size_t row = (i * 4) >> 9;
    float mk = mask[row];
    p.x = fmaxf((p.x * sc[c + 0] + sh[c + 0]) * mk, 0.f);
    p.y = fmaxf((p.y * sc[c + 1] + sh[c + 1]) * mk, 0.f);
    p.z = fmaxf((p.z * sc[c + 2] + sh[c + 2]) * mk, 0.f);
    p.w = fmaxf((p.w * sc[c + 3] + sh[c + 3]) * mk, 0.f);
    ((float4*)out)[i] = p;
  }
}

// ---------------------------------------------------------------------------
extern "C" void kernel_launch(void* const* d_in, const int* in_sizes, int n_in,
                              void* d_out, int out_size, void* d_ws, size_t ws_size,
                              hipStream_t stream) {
  const float* x    = (const float*)d_in[0];
  const float* adj  = (const float*)d_in[1];
  const float* gs   = (const float*)d_in[2];
  const int*   ssz  = (const int*)d_in[3];
  const float* mask = (const float*)d_in[4];
  const float* Wgfc = (const float*)d_in[5];
  const float* bgfc = (const float*)d_in[6];
  const float* Wgc  = (const float*)d_in[7];
  const float* bgc  = (const float*)d_in[8];
  const float* gn   = (const float*)d_in[9];
  const float* btn  = (const float*)d_in[10];
  const float* gg   = (const float*)d_in[11];
  const float* btg  = (const float*)d_in[12];
  float* out = (float*)d_out;

  // workspace layout (ws = 1 GiB confirmed r4 via poison-fill WRITE_SIZE)
  char* w = (char*)d_ws;
  float*          gt   = (float*)w;                               // 256 KiB
  unsigned short* gth  = (unsigned short*)(w + 262144);           // 128 KiB
  float*          gadd = (float*)(w + 393216);                    // 1 MiB
  int*            ns   = (int*)(w + 1441792);                     // 512 B
  float*          gsum = (float*)(w + 1442304);                   // 2 KiB
  float*          gsq  = (float*)(w + 1444352);                   // 2 KiB
  unsigned short* xh   = (unsigned short*)(w + ((size_t)2  << 20));  // 32 MiB
  unsigned short* wT   = (unsigned short*)(w + ((size_t)34 << 20));  // 4 MiB
  unsigned short* adjh = (unsigned short*)(w + ((size_t)40 << 20));  // 128 MiB
  unsigned short* supT = (unsigned short*)(w + ((size_t)168 << 20)); // up to 128 MiB

  long long avail = (long long)ws_size - (168ll << 20);
  int G = (avail > 0) ? (int)(avail / (2ll << 20)) : 0;
  if (G < 1) G = 1;
  if (G > 64) G = 64;
  if (G >= 8) G &= ~7;               // keep gc a multiple of 8 for XCD mapping

  k_decode<<<1, 64, 0, stream>>>(ssz, ns);
  k_gt<<<dim3(2, 32), 256, 0, stream>>>(gs, Wgfc, bgfc, gt, gth);
  k_gbn<<<8, 64, 0, stream>>>(gt, gg, btg, out + XOUT_ELEMS);
  hipMemsetAsync(gsum, 0, 4096, stream);

  k_cvt<<<2048, 256, 0, stream>>>(x, xh, (long)(16777216 / 8));
  k_cvt<<<4096, 256, 0, stream>>>(adj, adjh, (long)(67108864 / 8));
  k_cvt_w<<<dim3(32, 16, 4), 256, 0, stream>>>(Wgc, wT);
  k_gadd<<<16, 256, 0, stream>>>(gth, wT, gadd);

  for (int b0 = 0; b0 < 64; b0 += G) {
    int gc = 64 - b0; if (gc > G) gc = G;
    k_support<<<64 * gc, 256, 0, stream>>>(xh, wT, gadd, ns, supT, b0, gc);
    k_xout<<<16 * gc, 256, 0, stream>>>(adjh, supT, bgc, out, gsum, gsq, b0, gc);
  }

  k_norm<<<2048, 256, 0, stream>>>(gsum, gsq, gn, btn, mask, out);
}

// Round 10
// 745.189 us; speedup vs baseline: 1.1984x; 1.0996x over previous
//
#include <hip/hip_runtime.h>

#define DEVI __device__ __forceinline__

typedef __bf16 bf16x8 __attribute__((ext_vector_type(8)));
typedef float  f32x4  __attribute__((ext_vector_type(4)));
typedef unsigned short ushort8_t __attribute__((ext_vector_type(8)));

constexpr size_t XOUT_ELEMS = (size_t)64 * 512 * 512; // 16,777,216

DEVI unsigned short f2b(float f) {
  __bf16 h = (__bf16)f;               // RNE convert
  return __builtin_bit_cast(unsigned short, h);
}

// ---------------------------------------------------------------------------
// Decode subgraph_sizes (int64 vs int32 layout detection — passed r0-r6)
// ---------------------------------------------------------------------------
__global__ void k_decode(const int* __restrict__ ss, int* __restrict__ ns) {
  int t = threadIdx.x; // 0..63
  int odd = ss[2 * t + 1];
  unsigned long long bal = __ballot(odd == 0);
  bool is64 = (bal == 0xFFFFFFFFFFFFFFFFull);
  if (is64) {
    const long long* s64 = (const long long*)ss;
    ns[2 * t]     = (int)s64[2 * t];
    ns[2 * t + 1] = (int)s64[2 * t + 1];
  } else {
    ns[2 * t]     = ss[2 * t];
    ns[2 * t + 1] = ss[2 * t + 1];
  }
}

// ---------------------------------------------------------------------------
// gt (f32 for g_out) + gth (bf16 A operand for k_gadd)
// ---------------------------------------------------------------------------
__global__ void k_gt(const float* __restrict__ gs, const float* __restrict__ W,
                     const float* __restrict__ bias, float* __restrict__ gt,
                     unsigned short* __restrict__ gth) {
  __shared__ float srow[4][512];
  int r0  = blockIdx.y * 4;
  int col = blockIdx.x * 256 + threadIdx.x;
  for (int i = threadIdx.x; i < 4 * 512; i += 256)
    srow[i >> 9][i & 511] = gs[(size_t)r0 * 512 + i];
  __syncthreads();
  float acc[4] = {0.f, 0.f, 0.f, 0.f};
  for (int g = 0; g < 512; ++g) {
    float w = W[(size_t)g * 512 + col];
    acc[0] += srow[0][g] * w;
    acc[1] += srow[1][g] * w;
    acc[2] += srow[2][g] * w;
    acc[3] += srow[3][g] * w;
  }
  float bb = bias[col];
  #pragma unroll
  for (int r = 0; r < 4; ++r) {
    float v = acc[r] + bb;
    gt [(size_t)(r0 + r) * 512 + col] = v;
    gth[(size_t)(r0 + r) * 512 + col] = f2b(v);
  }
}

// ---------------------------------------------------------------------------
// g_out = relu(BN(gt)) -> d_out tail  (fp32-exact)
// ---------------------------------------------------------------------------
__global__ void k_gbn(const float* __restrict__ gt, const float* __restrict__ gamma,
                      const float* __restrict__ beta, float* __restrict__ gout) {
  int col = blockIdx.x * 64 + threadIdx.x;
  float s = 0.f, q = 0.f;
  for (int r = 0; r < 128; ++r) {
    float v = gt[(size_t)r * 512 + col];
    s += v; q += v * v;
  }
  float m   = s * (1.f / 128.f);
  float var = q * (1.f / 128.f) - m * m;
  float inv = 1.f / sqrtf(var + 1e-5f);
  float g = gamma[col], b = beta[col];
  for (int r = 0; r < 128; ++r) {
    float v = (gt[(size_t)r * 512 + col] - m) * inv * g + b;
    gout[(size_t)r * 512 + col] = fmaxf(v, 0.f);
  }
}

// ---------------------------------------------------------------------------
// f32 -> bf16 bulk convert
// ---------------------------------------------------------------------------
__global__ void k_cvt(const float* __restrict__ in, unsigned short* __restrict__ out,
                      long n8) {
  long i = (long)blockIdx.x * blockDim.x + threadIdx.x;
  long stride = (long)gridDim.x * blockDim.x;
  for (; i < n8; i += stride) {
    float4 a = ((const float4*)in)[2 * i];
    float4 b = ((const float4*)in)[2 * i + 1];
    ushort8_t o;
    o[0] = f2b(a.x); o[1] = f2b(a.y); o[2] = f2b(a.z); o[3] = f2b(a.w);
    o[4] = f2b(b.x); o[5] = f2b(b.y); o[6] = f2b(b.z); o[7] = f2b(b.w);
    *(ushort8_t*)&out[i * 8] = o;
  }
}

// ---------------------------------------------------------------------------
// W_gc [e][k=1024][o=512] f32  ->  wT [e][o=512][k=1024] bf16
// ---------------------------------------------------------------------------
__global__ void k_cvt_w(const float* __restrict__ W, unsigned short* __restrict__ wT) {
  __shared__ float t[32][33];
  int k0 = blockIdx.x * 32, o0 = blockIdx.y * 32, e = blockIdx.z;
  const float* Wb = W + (size_t)e * 1024 * 512;
  unsigned short* Tb = wT + (size_t)e * 512 * 1024;
  int tid = threadIdx.x;
  #pragma unroll
  for (int p = 0; p < 4; ++p) {
    int kl = p * 8 + (tid >> 5), ol = tid & 31;
    t[kl][ol] = Wb[(size_t)(k0 + kl) * 512 + o0 + ol];
  }
  __syncthreads();
  #pragma unroll
  for (int p = 0; p < 4; ++p) {
    int ol = p * 8 + (tid >> 5), kl = tid & 31;
    Tb[(size_t)(o0 + ol) * 1024 + k0 + kl] = f2b(t[kl][ol]);
  }
}

// ---------------------------------------------------------------------------
DEVI void gl_lds16(const unsigned short* g, unsigned short* l) {
  __builtin_amdgcn_global_load_lds(
      (const __attribute__((address_space(1))) void*)g,
      (__attribute__((address_space(3))) void*)l, 16, 0, 0);
}

// ---------------------------------------------------------------------------
// Small 128x128 core (m97 structure) — kept only for k_gadd (tiny GEMM).
// ---------------------------------------------------------------------------
DEVI int lds_idx(int row, int slot) {
  return row * 32 + ((slot ^ ((row >> 1) & 3)) << 3);
}

template <class FA, class FB>
DEVI void mfma_core(unsigned short* As, unsigned short* Bs, FA srcA, FB srcB,
                    int NT, f32x4 (&acc)[4][4]) {
  const int tid  = threadIdx.x;
  const int lane = tid & 63;
  const int wave = tid >> 6;
  const int wr = wave >> 1, wc = wave & 1;
  const int fr = lane & 15, fs = lane >> 4;

  const int c0 = tid,       r0 = c0 >> 2, s0 = (c0 & 3) ^ ((r0 >> 1) & 3);
  const int c1 = tid + 256, r1 = c1 >> 2, s1 = (c1 & 3) ^ ((r1 >> 1) & 3);

  int aoff[4], boff[4];
  #pragma unroll
  for (int i = 0; i < 4; ++i) {
    aoff[i] = lds_idx(wr * 64 + i * 16 + fr, fs);
    boff[i] = lds_idx(wc * 64 + i * 16 + fr, fs);
  }

  gl_lds16(srcA(r0, s0 * 8, 0), As + c0 * 8);
  gl_lds16(srcA(r1, s1 * 8, 0), As + c1 * 8);
  gl_lds16(srcB(r0, s0 * 8, 0), Bs + c0 * 8);
  gl_lds16(srcB(r1, s1 * 8, 0), Bs + c1 * 8);

  for (int kt = 0; kt < NT; ++kt) {
    __syncthreads();
    bf16x8 af[4], bfv[4];
    #pragma unroll
    for (int i = 0; i < 4; ++i) af[i] = *(const bf16x8*)(As + aoff[i]);
    #pragma unroll
    for (int j = 0; j < 4; ++j) bfv[j] = *(const bf16x8*)(Bs + boff[j]);
    if (kt + 1 < NT) {
      __syncthreads();
      gl_lds16(srcA(r0, s0 * 8, kt + 1), As + c0 * 8);
      gl_lds16(srcA(r1, s1 * 8, kt + 1), As + c1 * 8);
      gl_lds16(srcB(r0, s0 * 8, kt + 1), Bs + c0 * 8);
      gl_lds16(srcB(r1, s1 * 8, kt + 1), Bs + c1 * 8);
    }
    #pragma unroll
    for (int i = 0; i < 4; ++i)
      #pragma unroll
      for (int j = 0; j < 4; ++j)
        acc[i][j] = __builtin_amdgcn_mfma_f32_16x16x32_bf16(af[i], bfv[j], acc[i][j], 0, 0, 0);
  }
}

// ---------------------------------------------------------------------------
// k_gadd: gadd[m=2b+k][o'=e*512+o] = gth[m] . W_gc[e][512+..][o]  (f32 out)
// ---------------------------------------------------------------------------
__global__ __launch_bounds__(256) void k_gadd(
    const unsigned short* __restrict__ gth, const unsigned short* __restrict__ wT,
    float* __restrict__ gadd) {
  __shared__ __align__(16) unsigned short As[4096], Bs[4096];
  const int otile = blockIdx.x * 128;

  auto srcA = [=](int row, int kofs, int kt) -> const unsigned short* {
    return gth + (size_t)row * 512 + kt * 32 + kofs;
  };
  auto srcB = [=](int row, int kofs, int kt) -> const unsigned short* {
    int op = otile + row;
    int e = op >> 9, o = op & 511;
    return wT + (size_t)e * 524288 + (size_t)o * 1024 + 512 + kt * 32 + kofs;
  };

  f32x4 acc[4][4];
  #pragma unroll
  for (int i = 0; i < 4; ++i)
    #pragma unroll
    for (int j = 0; j < 4; ++j) acc[i][j] = (f32x4){0.f, 0.f, 0.f, 0.f};

  mfma_core(As, Bs, srcA, srcB, 16, acc);

  const int lane = threadIdx.x & 63, wave = threadIdx.x >> 6;
  const int wr = wave >> 1, wc = wave & 1, fr = lane & 15, fs = lane >> 4;
  #pragma unroll
  for (int i = 0; i < 4; ++i) {
    int m = wr * 64 + i * 16 + fs * 4;
    #pragma unroll
    for (int j = 0; j < 4; ++j) {
      int op = otile + wc * 64 + j * 16 + fr;
      #pragma unroll
      for (int r = 0; r < 4; ++r)
        gadd[(size_t)(m + r) * 2048 + op] = acc[i][j][r];
    }
  }
}

// ---------------------------------------------------------------------------
// 256x256 GEMM core, BK=32: 8 waves (2M x 4N), double-buffered LDS = 64 KiB
// (4 x 16 KiB tiles — under the 64 KiB static-LDS limit suspected in the r9
// crash). ONE barrier per K-tile:
//   STAGE(next buf) ; ds_read+MFMA(cur buf, 32 MFMA/wave) ; __syncthreads()
// The barrier's implicit vmcnt(0)+lgkmcnt(0) drain makes next buffer visible
// and protects cur-buf reuse. Tiles [256 rows][32 k] bf16, XOR swizzle
// slot^((row>>1)&3) (r6-verified, 0 conflicts), applied on the global source
// at staging (linear LDS dest, rule #21) and on the ds_read address.
// ---------------------------------------------------------------------------
template <class FA, class FB>
DEVI void core256(unsigned short* lds, FA srcA, FB srcB, int NT, f32x4 (&acc)[8][4]) {
  const int tid  = threadIdx.x;
  const int lane = tid & 63;
  const int wave = tid >> 6;
  const int wr = wave >> 2, wcol = wave & 3;
  const int fr = lane & 15, fs = lane >> 4;

  // buffers (ushort offsets): As0 0 | Bs0 8192 | As1 16384 | Bs1 24576
  // staging: 1024 x 16B chunks per tile side, 2 per thread.
  int crow[2], cslot[2];
  #pragma unroll
  for (int t = 0; t < 2; ++t) {
    int c = tid + t * 512;
    crow[t]  = c >> 2;
    cslot[t] = (c & 3) ^ ((crow[t] >> 1) & 3);   // pre-swizzled global k-slot
  }

  int aoff[8], boff[4];
  #pragma unroll
  for (int i = 0; i < 8; ++i) {
    int row = wr * 128 + i * 16 + fr;
    aoff[i] = row * 32 + ((fs ^ ((row >> 1) & 3)) << 3);
  }
  #pragma unroll
  for (int j = 0; j < 4; ++j) {
    int row = wcol * 64 + j * 16 + fr;
    boff[j] = row * 32 + ((fs ^ ((row >> 1) & 3)) << 3);
  }

  // prologue: stage K-tile 0 into buf 0
  #pragma unroll
  for (int t = 0; t < 2; ++t) {
    int c = tid + t * 512;
    gl_lds16(srcA(crow[t], cslot[t] * 8, 0), lds + c * 8);
    gl_lds16(srcB(crow[t], cslot[t] * 8, 0), lds + 8192 + c * 8);
  }
  __syncthreads();

  int cur = 0;
  for (int kt = 0; kt < NT; ++kt) {
    unsigned short* Ab = lds + (cur ? 16384 : 0);
    unsigned short* Bb = Ab + 8192;
    if (kt + 1 < NT) {
      unsigned short* An = lds + (cur ? 0 : 16384);
      unsigned short* Bn = An + 8192;
      #pragma unroll
      for (int t = 0; t < 2; ++t) {
        int c = tid + t * 512;
        gl_lds16(srcA(crow[t], cslot[t] * 8, kt + 1), An + c * 8);
        gl_lds16(srcB(crow[t], cslot[t] * 8, kt + 1), Bn + c * 8);
      }
    }
    bf16x8 af[8], bfv[4];
    #pragma unroll
    for (int i = 0; i < 8; ++i) af[i] = *(const bf16x8*)(Ab + aoff[i]);
    #pragma unroll
    for (int j = 0; j < 4; ++j) bfv[j] = *(const bf16x8*)(Bb + boff[j]);
    #pragma unroll
    for (int i = 0; i < 8; ++i)
      #pragma unroll
      for (int j = 0; j < 4; ++j)
        acc[i][j] = __builtin_amdgcn_mfma_f32_16x16x32_bf16(af[i], bfv[j], acc[i][j], 0, 0, 0);
    __syncthreads();   // drains vmcnt (next stage) + all waves done reading cur
    cur ^= 1;
  }
}

// ---------------------------------------------------------------------------
// GEMM1 (256², BK=32): support^T[zi*4+e][o][m] = (x[b] @ Wx[e])^T + gadd-sel
// grid 1024: xcd=bid&7, j=bid>>3: et=j&15 (e=et>>2, tile=et&3), bgrp=j>>4;
// zi = bgrp*8+xcd -> all tiles of a batch pinned to one XCD.
// ---------------------------------------------------------------------------
__global__ __launch_bounds__(512) void k_support(
    const unsigned short* __restrict__ xh, const unsigned short* __restrict__ wT,
    const float* __restrict__ gadd, const int* __restrict__ ns,
    unsigned short* __restrict__ supT) {
  __shared__ __align__(16) unsigned short lds[32768];   // 64 KiB
  const int xcd = blockIdx.x & 7;
  const int jj  = blockIdx.x >> 3;
  const int et  = jj & 15;
  const int e    = et >> 2;
  const int tile = et & 3;
  const int zi  = (jj >> 4) * 8 + xcd;
  const int row0  = (tile >> 1) * 256;
  const int otile = (tile & 1) * 256;
  const int b = zi;
  const int n1  = ns[2 * b];
  const int n12 = n1 + ns[2 * b + 1];
  const unsigned short* xb = xh + (size_t)b * 262144;
  const unsigned short* wb = wT + (size_t)e * 524288;

  auto srcA = [=](int r, int koff, int kt) -> const unsigned short* {
    return xb + (size_t)(row0 + r) * 512 + kt * 32 + koff;
  };
  auto srcB = [=](int r, int koff, int kt) -> const unsigned short* {
    return wb + (size_t)(otile + r) * 1024 + kt * 32 + koff;
  };

  f32x4 acc[8][4];
  #pragma unroll
  for (int i = 0; i < 8; ++i)
    #pragma unroll
    for (int j = 0; j < 4; ++j) acc[i][j] = (f32x4){0.f, 0.f, 0.f, 0.f};

  core256(lds, srcA, srcB, 16, acc);

  const int lane = threadIdx.x & 63, wave = threadIdx.x >> 6;
  const int wr = wave >> 2, wcol = wave & 3, fr = lane & 15, fs = lane >> 4;
  unsigned short* sp = supT + (size_t)(zi * 4 + e) * 262144;
  #pragma unroll
  for (int j = 0; j < 4; ++j) {
    int o = otile + wcol * 64 + j * 16 + fr;
    float g0 = gadd[(size_t)(2 * b)     * 2048 + e * 512 + o];
    float g1 = gadd[(size_t)(2 * b + 1) * 2048 + e * 512 + o];
    #pragma unroll
    for (int i = 0; i < 8; ++i) {
      int m = row0 + wr * 128 + i * 16 + fs * 4;
      ushort4 h;
      #pragma unroll
      for (int r = 0; r < 4; ++r) {
        int mr = m + r;
        float add = (mr < n1) ? g0 : ((mr < n12) ? g1 : 0.f);
        ((unsigned short*)&h)[r] = f2b(acc[i][j][r] + add);
      }
      *(ushort4*)&sp[(size_t)o * 512 + m] = h;
    }
  }
}

// ---------------------------------------------------------------------------
// GEMM2 (256², BK=32): out[b][n][o] = sum_{e,m} adj[b,e][n][m]*supT[e][o][m]
// + b_gc. grid 256: xcd=bid&7, j=bid>>3: tile=j&3, bgrp=j>>2; zi=bgrp*8+xcd.
// adjh[b]+supT[b] = 4 MB pinned in the XCD's L2.
// ---------------------------------------------------------------------------
__global__ __launch_bounds__(512) void k_xout(
    const unsigned short* __restrict__ adjh, const unsigned short* __restrict__ supT,
    const float* __restrict__ bgc, float* __restrict__ out,
    float* __restrict__ gsum, float* __restrict__ gsq) {
  __shared__ __align__(16) unsigned short lds[32768];   // 64 KiB
  const int xcd = blockIdx.x & 7;
  const int jj  = blockIdx.x >> 3;
  const int tile = jj & 3;
  const int zi  = (jj >> 2) * 8 + xcd;
  const int row0  = (tile >> 1) * 256;
  const int otile = (tile & 1) * 256;
  const int b = zi;
  const unsigned short* ab = adjh + (size_t)b * 4 * 262144;
  const unsigned short* sb = supT + (size_t)zi * 4 * 262144;

  auto srcA = [=](int r, int koff, int kt) -> const unsigned short* {
    int k = kt * 32 + koff;                 // 0..2047 = e*512 + m
    int e = k >> 9, m = k & 511;
    return ab + ((size_t)e * 512 + row0 + r) * 512 + m;
  };
  auto srcB = [=](int r, int koff, int kt) -> const unsigned short* {
    int k = kt * 32 + koff;
    int e = k >> 9, m = k & 511;
    return sb + (size_t)e * 262144 + (size_t)(otile + r) * 512 + m;
  };

  f32x4 acc[8][4];
  #pragma unroll
  for (int i = 0; i < 8; ++i)
    #pragma unroll
    for (int j = 0; j < 4; ++j) acc[i][j] = (f32x4){0.f, 0.f, 0.f, 0.f};

  core256(lds, srcA, srcB, 64, acc);

  const int tid = threadIdx.x;
  const int lane = tid & 63, wave = tid >> 6;
  const int wr = wave >> 2, wcol = wave & 3, fr = lane & 15, fs = lane >> 4;

  float cs[4], cq[4];
  #pragma unroll
  for (int j = 0; j < 4; ++j) {
    int o = otile + wcol * 64 + j * 16 + fr;
    float bb = bgc[o];
    float s = 0.f, q = 0.f;
    #pragma unroll
    for (int i = 0; i < 8; ++i) {
      int nb = row0 + wr * 128 + i * 16 + fs * 4;
      #pragma unroll
      for (int r = 0; r < 4; ++r) {
        float v = acc[i][j][r] + bb;
        out[((size_t)b * 512 + nb + r) * 512 + o] = v;
        s += v; q += v * v;
      }
    }
    cs[j] = s; cq[j] = q;
  }

  // per-column stats: LDS reduce (512 floats: 256 sum + 256 sumsq) -> global
  float* red = (float*)lds;
  __syncthreads();
  red[tid] = 0.f;
  __syncthreads();
  #pragma unroll
  for (int j = 0; j < 4; ++j) {
    int cl = wcol * 64 + j * 16 + fr;
    atomicAdd(&red[cl], cs[j]);
    atomicAdd(&red[256 + cl], cq[j]);
  }
  __syncthreads();
  if (tid < 256) {
    atomicAdd(&gsum[otile + tid], red[tid]);
    atomicAdd(&gsq[otile + tid],  red[256 + tid]);
  }
}

// ---------------------------------------------------------------------------
// In-place BN + mask + relu
// ---------------------------------------------------------------------------
__global__ void k_norm(const float* __restrict__ gsum, const float* __restrict__ gsq,
                       const float* __restrict__ gamma, const float* __restrict__ beta,
                       const float* __restrict__ mask, float* __restrict__ out) {
  __shared__ float sc[512], sh[512];
  for (int c = threadIdx.x; c < 512; c += blockDim.x) {
    float m   = gsum[c] * (1.f / 32768.f);
    float var = gsq[c] * (1.f / 32768.f) - m * m;
    float inv = 1.f / sqrtf(var + 1e-5f);
    float g = gamma[c] * inv;
    sc[c] = g;
    sh[c] = beta[c] - m * g;
  }
  __syncthreads();
  size_t i0 = (size_t)blockIdx.x * blockDim.x + threadIdx.x;
  size_t stride = (size_t)gridDim.x * blockDim.x;
  size_t n4 = XOUT_ELEMS / 4;
  for (size_t i = i0; i < n4; i += stride) {
    float4 p = ((const float4*)out)[i];
    int c = (int)((i * 4) & 511);
    size_t row = (i * 4) >> 9;
    float mk = mask[row];
    p.x = fmaxf((p.x * sc[c + 0] + sh[c + 0]) * mk, 0.f);
    p.y = fmaxf((p.y * sc[c + 1] + sh[c + 1]) * mk, 0.f);
    p.z = fmaxf((p.z * sc[c + 2] + sh[c + 2]) * mk, 0.f);
    p.w = fmaxf((p.w * sc[c + 3] + sh[c + 3]) * mk, 0.f);
    ((float4*)out)[i] = p;
  }
}

// ---------------------------------------------------------------------------
extern "C" void kernel_launch(void* const* d_in, const int* in_sizes, int n_in,
                              void* d_out, int out_size, void* d_ws, size_t ws_size,
                              hipStream_t stream) {
  const float* x    = (const float*)d_in[0];
  const float* adj  = (const float*)d_in[1];
  const float* gs   = (const float*)d_in[2];
  const int*   ssz  = (const int*)d_in[3];
  const float* mask = (const float*)d_in[4];
  const float* Wgfc = (const float*)d_in[5];
  const float* bgfc = (const float*)d_in[6];
  const float* Wgc  = (const float*)d_in[7];
  const float* bgc  = (const float*)d_in[8];
  const float* gn   = (const float*)d_in[9];
  const float* btn  = (const float*)d_in[10];
  const float* gg   = (const float*)d_in[11];
  const float* btg  = (const float*)d_in[12];
  float* out = (float*)d_out;

  // workspace layout (ws = 1 GiB confirmed r4/r6 via poison-fill WRITE_SIZE)
  char* w = (char*)d_ws;
  float*          gt   = (float*)w;                               // 256 KiB
  unsigned short* gth  = (unsigned short*)(w + 262144);           // 128 KiB
  float*          gadd = (float*)(w + 393216);                    // 1 MiB
  int*            ns   = (int*)(w + 1441792);                     // 512 B
  float*          gsum = (float*)(w + 1442304);                   // 2 KiB
  float*          gsq  = (float*)(w + 1444352);                   // 2 KiB
  unsigned short* xh   = (unsigned short*)(w + ((size_t)2  << 20));  // 32 MiB
  unsigned short* wT   = (unsigned short*)(w + ((size_t)34 << 20));  // 4 MiB
  unsigned short* adjh = (unsigned short*)(w + ((size_t)40 << 20));  // 128 MiB
  unsigned short* supT = (unsigned short*)(w + ((size_t)168 << 20)); // 128 MiB

  k_decode<<<1, 64, 0, stream>>>(ssz, ns);
  k_gt<<<dim3(2, 32), 256, 0, stream>>>(gs, Wgfc, bgfc, gt, gth);
  k_gbn<<<8, 64, 0, stream>>>(gt, gg, btg, out + XOUT_ELEMS);
  hipMemsetAsync(gsum, 0, 4096, stream);

  k_cvt<<<2048, 256, 0, stream>>>(x, xh, (long)(16777216 / 8));
  k_cvt<<<4096, 256, 0, stream>>>(adj, adjh, (long)(67108864 / 8));
  k_cvt_w<<<dim3(32, 16, 4), 256, 0, stream>>>(Wgc, wT);
  k_gadd<<<16, 256, 0, stream>>>(gth, wT, gadd);

  k_support<<<1024, 512, 0, stream>>>(xh, wT, gadd, ns, supT);
  k_xout<<<256, 512, 0, stream>>>(adjh, supT, bgc, out, gsum, gsq);

  k_norm<<<2048, 256, 0, stream>>>(gsum, gsq, gn, btn, mask, out);
}

// Round 12
// 719.584 us; speedup vs baseline: 1.2410x; 1.0356x over previous
//
#include <hip/hip_runtime.h>

#define DEVI __device__ __forceinline__

typedef __bf16 bf16x8 __attribute__((ext_vector_type(8)));
typedef float  f32x4  __attribute__((ext_vector_type(4)));
typedef unsigned short ushort8_t __attribute__((ext_vector_type(8)));

constexpr size_t XOUT_ELEMS = (size_t)64 * 512 * 512; // 16,777,216

DEVI unsigned short f2b(float f) {
  __bf16 h = (__bf16)f;               // RNE convert
  return __builtin_bit_cast(unsigned short, h);
}

// ---------------------------------------------------------------------------
// Decode subgraph_sizes (int64 vs int32 layout detection — passed r0-r10)
// ---------------------------------------------------------------------------
__global__ void k_decode(const int* __restrict__ ss, int* __restrict__ ns) {
  int t = threadIdx.x; // 0..63
  int odd = ss[2 * t + 1];
  unsigned long long bal = __ballot(odd == 0);
  bool is64 = (bal == 0xFFFFFFFFFFFFFFFFull);
  if (is64) {
    const long long* s64 = (const long long*)ss;
    ns[2 * t]     = (int)s64[2 * t];
    ns[2 * t + 1] = (int)s64[2 * t + 1];
  } else {
    ns[2 * t]     = ss[2 * t];
    ns[2 * t + 1] = ss[2 * t + 1];
  }
}

// ---------------------------------------------------------------------------
// gt (f32 for g_out) + gth (bf16 A operand for k_gadd)
// ---------------------------------------------------------------------------
__global__ void k_gt(const float* __restrict__ gs, const float* __restrict__ W,
                     const float* __restrict__ bias, float* __restrict__ gt,
                     unsigned short* __restrict__ gth) {
  __shared__ float srow[4][512];
  int r0  = blockIdx.y * 4;
  int col = blockIdx.x * 256 + threadIdx.x;
  for (int i = threadIdx.x; i < 4 * 512; i += 256)
    srow[i >> 9][i & 511] = gs[(size_t)r0 * 512 + i];
  __syncthreads();
  float acc[4] = {0.f, 0.f, 0.f, 0.f};
  for (int g = 0; g < 512; ++g) {
    float w = W[(size_t)g * 512 + col];
    acc[0] += srow[0][g] * w;
    acc[1] += srow[1][g] * w;
    acc[2] += srow[2][g] * w;
    acc[3] += srow[3][g] * w;
  }
  float bb = bias[col];
  #pragma unroll
  for (int r = 0; r < 4; ++r) {
    float v = acc[r] + bb;
    gt [(size_t)(r0 + r) * 512 + col] = v;
    gth[(size_t)(r0 + r) * 512 + col] = f2b(v);
  }
}

// ---------------------------------------------------------------------------
// g_out = relu(BN(gt)) -> d_out tail  (fp32-exact)
// ---------------------------------------------------------------------------
__global__ void k_gbn(const float* __restrict__ gt, const float* __restrict__ gamma,
                      const float* __restrict__ beta, float* __restrict__ gout) {
  int col = blockIdx.x * 64 + threadIdx.x;
  float s = 0.f, q = 0.f;
  for (int r = 0; r < 128; ++r) {
    float v = gt[(size_t)r * 512 + col];
    s += v; q += v * v;
  }
  float m   = s * (1.f / 128.f);
  float var = q * (1.f / 128.f) - m * m;
  float inv = 1.f / sqrtf(var + 1e-5f);
  float g = gamma[col], b = beta[col];
  for (int r = 0; r < 128; ++r) {
    float v = (gt[(size_t)r * 512 + col] - m) * inv * g + b;
    gout[(size_t)r * 512 + col] = fmaxf(v, 0.f);
  }
}

// ---------------------------------------------------------------------------
// W_gc [e][k=1024][o=512] f32  ->  wT [e][o=512][k=1024] bf16
// ---------------------------------------------------------------------------
__global__ void k_cvt_w(const float* __restrict__ W, unsigned short* __restrict__ wT) {
  __shared__ float t[32][33];
  int k0 = blockIdx.x * 32, o0 = blockIdx.y * 32, e = blockIdx.z;
  const float* Wb = W + (size_t)e * 1024 * 512;
  unsigned short* Tb = wT + (size_t)e * 512 * 1024;
  int tid = threadIdx.x;
  #pragma unroll
  for (int p = 0; p < 4; ++p) {
    int kl = p * 8 + (tid >> 5), ol = tid & 31;
    t[kl][ol] = Wb[(size_t)(k0 + kl) * 512 + o0 + ol];
  }
  __syncthreads();
  #pragma unroll
  for (int p = 0; p < 4; ++p) {
    int ol = p * 8 + (tid >> 5), kl = tid & 31;
    Tb[(size_t)(o0 + ol) * 1024 + k0 + kl] = f2b(t[kl][ol]);
  }
}

// ---------------------------------------------------------------------------
DEVI void gl_lds16(const unsigned short* g, unsigned short* l) {
  __builtin_amdgcn_global_load_lds(
      (const __attribute__((address_space(1))) void*)g,
      (__attribute__((address_space(3))) void*)l, 16, 0, 0);
}

// ---------------------------------------------------------------------------
// Small 128x128 core (m97 structure) — kept only for k_gadd (tiny GEMM).
// ---------------------------------------------------------------------------
DEVI int lds_idx(int row, int slot) {
  return row * 32 + ((slot ^ ((row >> 1) & 3)) << 3);
}

template <class FA, class FB>
DEVI void mfma_core(unsigned short* As, unsigned short* Bs, FA srcA, FB srcB,
                    int NT, f32x4 (&acc)[4][4]) {
  const int tid  = threadIdx.x;
  const int lane = tid & 63;
  const int wave = tid >> 6;
  const int wr = wave >> 1, wc = wave & 1;
  const int fr = lane & 15, fs = lane >> 4;

  const int c0 = tid,       r0 = c0 >> 2, s0 = (c0 & 3) ^ ((r0 >> 1) & 3);
  const int c1 = tid + 256, r1 = c1 >> 2, s1 = (c1 & 3) ^ ((r1 >> 1) & 3);

  int aoff[4], boff[4];
  #pragma unroll
  for (int i = 0; i < 4; ++i) {
    aoff[i] = lds_idx(wr * 64 + i * 16 + fr, fs);
    boff[i] = lds_idx(wc * 64 + i * 16 + fr, fs);
  }

  gl_lds16(srcA(r0, s0 * 8, 0), As + c0 * 8);
  gl_lds16(srcA(r1, s1 * 8, 0), As + c1 * 8);
  gl_lds16(srcB(r0, s0 * 8, 0), Bs + c0 * 8);
  gl_lds16(srcB(r1, s1 * 8, 0), Bs + c1 * 8);

  for (int kt = 0; kt < NT; ++kt) {
    __syncthreads();
    bf16x8 af[4], bfv[4];
    #pragma unroll
    for (int i = 0; i < 4; ++i) af[i] = *(const bf16x8*)(As + aoff[i]);
    #pragma unroll
    for (int j = 0; j < 4; ++j) bfv[j] = *(const bf16x8*)(Bs + boff[j]);
    if (kt + 1 < NT) {
      __syncthreads();
      gl_lds16(srcA(r0, s0 * 8, kt + 1), As + c0 * 8);
      gl_lds16(srcA(r1, s1 * 8, kt + 1), As + c1 * 8);
      gl_lds16(srcB(r0, s0 * 8, kt + 1), Bs + c0 * 8);
      gl_lds16(srcB(r1, s1 * 8, kt + 1), Bs + c1 * 8);
    }
    #pragma unroll
    for (int i = 0; i < 4; ++i)
      #pragma unroll
      for (int j = 0; j < 4; ++j)
        acc[i][j] = __builtin_amdgcn_mfma_f32_16x16x32_bf16(af[i], bfv[j], acc[i][j], 0, 0, 0);
  }
}

// ---------------------------------------------------------------------------
// k_gadd: gadd[m=2b+k][o'=e*512+o] = gth[m] . W_gc[e][512+..][o]  (f32 out)
// ---------------------------------------------------------------------------
__global__ __launch_bounds__(256) void k_gadd(
    const unsigned short* __restrict__ gth, const unsigned short* __restrict__ wT,
    float* __restrict__ gadd) {
  __shared__ __align__(16) unsigned short As[4096], Bs[4096];
  const int otile = blockIdx.x * 128;

  auto srcA = [=](int row, int kofs, int kt) -> const unsigned short* {
    return gth + (size_t)row * 512 + kt * 32 + kofs;
  };
  auto srcB = [=](int row, int kofs, int kt) -> const unsigned short* {
    int op = otile + row;
    int e = op >> 9, o = op & 511;
    return wT + (size_t)e * 524288 + (size_t)o * 1024 + 512 + kt * 32 + kofs;
  };

  f32x4 acc[4][4];
  #pragma unroll
  for (int i = 0; i < 4; ++i)
    #pragma unroll
    for (int j = 0; j < 4; ++j) acc[i][j] = (f32x4){0.f, 0.f, 0.f, 0.f};

  mfma_core(As, Bs, srcA, srcB, 16, acc);

  const int lane = threadIdx.x & 63, wave = threadIdx.x >> 6;
  const int wr = wave >> 1, wc = wave & 1, fr = lane & 15, fs = lane >> 4;
  #pragma unroll
  for (int i = 0; i < 4; ++i) {
    int m = wr * 64 + i * 16 + fs * 4;
    #pragma unroll
    for (int j = 0; j < 4; ++j) {
      int op = otile + wc * 64 + j * 16 + fr;
      #pragma unroll
      for (int r = 0; r < 4; ++r)
        gadd[(size_t)(m + r) * 2048 + op] = acc[i][j][r];
    }
  }
}

// ---------------------------------------------------------------------------
// 256x256 GEMM core, BK=32, fused-convert A: A is read from the ORIGINAL f32
// input (reg-staged: issue float4 loads early -> 32 MFMA hides HBM latency ->
// cvt+ds_write_b128 late, T14), B (bf16) via global_load_lds. LDS = 64 KiB
// (4 x 16 KiB, double-buffered). ONE barrier per K-tile; the barrier's
// vmcnt/lgkm drain publishes both the B gl_lds and the A ds_writes.
// (row,slot) LDS mapping identical to r10: elem slot s of row lives at
// row*32 + ((s ^ ((row>>1)&3))<<3) — write-side XOR on ds_write, pre-swizzled
// global source for gl_lds (rule #21).
// ---------------------------------------------------------------------------
template <class FA, class FB>
DEVI void core256(unsigned short* lds, FA srcA, FB srcB, int NT, f32x4 (&acc)[8][4]) {
  const int tid  = threadIdx.x;
  const int lane = tid & 63;
  const int wave = tid >> 6;
  const int wr = wave >> 2, wcol = wave & 3;
  const int fr = lane & 15, fs = lane >> 4;

  // A chunks (reg-staged): c = tid + t*512; row=c>>2, s=c&3 (natural order);
  // LDS dest applies the XOR swizzle.
  int arow[2], aslot[2], aidx[2];
  #pragma unroll
  for (int t = 0; t < 2; ++t) {
    int c = tid + t * 512;
    arow[t] = c >> 2;
    aslot[t] = c & 3;
    aidx[t] = arow[t] * 32 + ((aslot[t] ^ ((arow[t] >> 1) & 3)) << 3);
  }
  // B chunks (gl_lds): linear LDS dest, pre-swizzled global k-slot.
  int brow[2], bslot[2];
  #pragma unroll
  for (int t = 0; t < 2; ++t) {
    int c = tid + t * 512;
    brow[t]  = c >> 2;
    bslot[t] = (c & 3) ^ ((brow[t] >> 1) & 3);
  }

  int aoff[8], boff[4];
  #pragma unroll
  for (int i = 0; i < 8; ++i) {
    int row = wr * 128 + i * 16 + fr;
    aoff[i] = row * 32 + ((fs ^ ((row >> 1) & 3)) << 3);
  }
  #pragma unroll
  for (int j = 0; j < 4; ++j) {
    int row = wcol * 64 + j * 16 + fr;
    boff[j] = row * 32 + ((fs ^ ((row >> 1) & 3)) << 3);
  }

  // prologue: stage K-tile 0 into buf 0 (A: load+cvt+write; B: gl_lds)
  #pragma unroll
  for (int t = 0; t < 2; ++t) {
    const float* p = srcA(arow[t], aslot[t] * 8, 0);
    float4 v0 = *(const float4*)p;
    float4 v1 = *(const float4*)(p + 4);
    ushort8_t h;
    h[0] = f2b(v0.x); h[1] = f2b(v0.y); h[2] = f2b(v0.z); h[3] = f2b(v0.w);
    h[4] = f2b(v1.x); h[5] = f2b(v1.y); h[6] = f2b(v1.z); h[7] = f2b(v1.w);
    *(ushort8_t*)(lds + aidx[t]) = h;
  }
  #pragma unroll
  for (int t = 0; t < 2; ++t) {
    int c = tid + t * 512;
    gl_lds16(srcB(brow[t], bslot[t] * 8, 0), lds + 8192 + c * 8);
  }
  __syncthreads();

  int cur = 0;
  for (int kt = 0; kt < NT; ++kt) {
    unsigned short* Ab = lds + (cur ? 16384 : 0);
    unsigned short* Bb = Ab + 8192;
    const bool more = (kt + 1 < NT);
    float4 fa0_0, fa0_1, fa1_0, fa1_1;
    if (more) {
      // issue A f32 loads EARLY (latency hides under the MFMA block)
      const float* p0 = srcA(arow[0], aslot[0] * 8, kt + 1);
      const float* p1 = srcA(arow[1], aslot[1] * 8, kt + 1);
      fa0_0 = *(const float4*)p0; fa0_1 = *(const float4*)(p0 + 4);
      fa1_0 = *(const float4*)p1; fa1_1 = *(const float4*)(p1 + 4);
      // B async direct-to-LDS
      unsigned short* Bn = lds + (cur ? 0 : 16384) + 8192;
      #pragma unroll
      for (int t = 0; t < 2; ++t) {
        int c = tid + t * 512;
        gl_lds16(srcB(brow[t], bslot[t] * 8, kt + 1), Bn + c * 8);
      }
    }
    bf16x8 af[8], bfv[4];
    #pragma unroll
    for (int i = 0; i < 8; ++i) af[i] = *(const bf16x8*)(Ab + aoff[i]);
    #pragma unroll
    for (int j = 0; j < 4; ++j) bfv[j] = *(const bf16x8*)(Bb + boff[j]);
    #pragma unroll
    for (int i = 0; i < 8; ++i)
      #pragma unroll
      for (int j = 0; j < 4; ++j)
        acc[i][j] = __builtin_amdgcn_mfma_f32_16x16x32_bf16(af[i], bfv[j], acc[i][j], 0, 0, 0);
    if (more) {
      // cvt + ds_write LATE (T14); loads are long complete by now
      unsigned short* An = lds + (cur ? 0 : 16384);
      ushort8_t h0, h1;
      h0[0] = f2b(fa0_0.x); h0[1] = f2b(fa0_0.y); h0[2] = f2b(fa0_0.z); h0[3] = f2b(fa0_0.w);
      h0[4] = f2b(fa0_1.x); h0[5] = f2b(fa0_1.y); h0[6] = f2b(fa0_1.z); h0[7] = f2b(fa0_1.w);
      h1[0] = f2b(fa1_0.x); h1[1] = f2b(fa1_0.y); h1[2] = f2b(fa1_0.z); h1[3] = f2b(fa1_0.w);
      h1[4] = f2b(fa1_1.x); h1[5] = f2b(fa1_1.y); h1[6] = f2b(fa1_1.z); h1[7] = f2b(fa1_1.w);
      *(ushort8_t*)(An + aidx[0]) = h0;
      *(ushort8_t*)(An + aidx[1]) = h1;
    }
    __syncthreads();   // publishes A ds_writes + B gl_lds; protects cur reuse
    cur ^= 1;
  }
}

// ---------------------------------------------------------------------------
// GEMM1 (256², BK=32, fused cvt): support^T[zi*4+e][o][m] =
//   (x[b] @ Wx[e])^T + gadd-select.  A = x (f32, reg-staged), B = wT (bf16).
// grid 1024: xcd=bid&7, j=bid>>3: et=j&15 (e=et>>2, tile=et&3), bgrp=j>>4;
// zi = bgrp*8+xcd -> all tiles of a batch pinned to one XCD.
// ---------------------------------------------------------------------------
__global__ __launch_bounds__(512) void k_support(
    const float* __restrict__ x, const unsigned short* __restrict__ wT,
    const float* __restrict__ gadd, const int* __restrict__ ns,
    unsigned short* __restrict__ supT) {
  __shared__ __align__(16) unsigned short lds[32768];   // 64 KiB
  const int xcd = blockIdx.x & 7;
  const int jj  = blockIdx.x >> 3;
  const int et  = jj & 15;
  const int e    = et >> 2;
  const int tile = et & 3;
  const int zi  = (jj >> 4) * 8 + xcd;
  const int row0  = (tile >> 1) * 256;
  const int otile = (tile & 1) * 256;
  const int b = zi;
  const int n1  = ns[2 * b];
  const int n12 = n1 + ns[2 * b + 1];
  const float* xb = x + (size_t)b * 262144;
  const unsigned short* wb = wT + (size_t)e * 524288;

  auto srcA = [=](int r, int koff, int kt) -> const float* {
    return xb + (size_t)(row0 + r) * 512 + kt * 32 + koff;
  };
  auto srcB = [=](int r, int koff, int kt) -> const unsigned short* {
    return wb + (size_t)(otile + r) * 1024 + kt * 32 + koff;
  };

  f32x4 acc[8][4];
  #pragma unroll
  for (int i = 0; i < 8; ++i)
    #pragma unroll
    for (int j = 0; j < 4; ++j) acc[i][j] = (f32x4){0.f, 0.f, 0.f, 0.f};

  core256(lds, srcA, srcB, 16, acc);

  const int lane = threadIdx.x & 63, wave = threadIdx.x >> 6;
  const int wr = wave >> 2, wcol = wave & 3, fr = lane & 15, fs = lane >> 4;
  unsigned short* sp = supT + (size_t)(zi * 4 + e) * 262144;
  #pragma unroll
  for (int j = 0; j < 4; ++j) {
    int o = otile + wcol * 64 + j * 16 + fr;
    float g0 = gadd[(size_t)(2 * b)     * 2048 + e * 512 + o];
    float g1 = gadd[(size_t)(2 * b + 1) * 2048 + e * 512 + o];
    #pragma unroll
    for (int i = 0; i < 8; ++i) {
      int m = row0 + wr * 128 + i * 16 + fs * 4;
      ushort4 h;
      #pragma unroll
      for (int r = 0; r < 4; ++r) {
        int mr = m + r;
        float add = (mr < n1) ? g0 : ((mr < n12) ? g1 : 0.f);
        ((unsigned short*)&h)[r] = f2b(acc[i][j][r] + add);
      }
      *(ushort4*)&sp[(size_t)o * 512 + m] = h;
    }
  }
}

// ---------------------------------------------------------------------------
// GEMM2 (256², BK=32, fused cvt): out[b][n][o] =
//   sum_{e,m} adj[b,e][n][m]*supT[e][o][m] + b_gc.
// A = adj (f32, reg-staged), B = supT (bf16). grid 256: xcd=bid&7,
// j=bid>>3: tile=j&3, bgrp=j>>2; zi=bgrp*8+xcd (XCD-pinned working set).
// ---------------------------------------------------------------------------
__global__ __launch_bounds__(512) void k_xout(
    const float* __restrict__ adj, const unsigned short* __restrict__ supT,
    const float* __restrict__ bgc, float* __restrict__ out,
    float* __restrict__ gsum, float* __restrict__ gsq) {
  __shared__ __align__(16) unsigned short lds[32768];   // 64 KiB
  const int xcd = blockIdx.x & 7;
  const int jj  = blockIdx.x >> 3;
  const int tile = jj & 3;
  const int zi  = (jj >> 2) * 8 + xcd;
  const int row0  = (tile >> 1) * 256;
  const int otile = (tile & 1) * 256;
  const int b = zi;
  const float* ab = adj + (size_t)b * 1048576;
  const unsigned short* sb = supT + (size_t)zi * 4 * 262144;

  auto srcA = [=](int r, int koff, int kt) -> const float* {
    int k = kt * 32 + koff;                 // 0..2047 = e*512 + m
    int e = k >> 9, m = k & 511;
    return ab + ((size_t)e * 512 + row0 + r) * 512 + m;
  };
  auto srcB = [=](int r, int koff, int kt) -> const unsigned short* {
    int k = kt * 32 + koff;
    int e = k >> 9, m = k & 511;
    return sb + (size_t)e * 262144 + (size_t)(otile + r) * 512 + m;
  };

  f32x4 acc[8][4];
  #pragma unroll
  for (int i = 0; i < 8; ++i)
    #pragma unroll
    for (int j = 0; j < 4; ++j) acc[i][j] = (f32x4){0.f, 0.f, 0.f, 0.f};

  core256(lds, srcA, srcB, 64, acc);

  const int tid = threadIdx.x;
  const int lane = tid & 63, wave = tid >> 6;
  const int wr = wave >> 2, wcol = wave & 3, fr = lane & 15, fs = lane >> 4;

  float cs[4], cq[4];
  #pragma unroll
  for (int j = 0; j < 4; ++j) {
    int o = otile + wcol * 64 + j * 16 + fr;
    float bb = bgc[o];
    float s = 0.f, q = 0.f;
    #pragma unroll
    for (int i = 0; i < 8; ++i) {
      int nb = row0 + wr * 128 + i * 16 + fs * 4;
      #pragma unroll
      for (int r = 0; r < 4; ++r) {
        float v = acc[i][j][r] + bb;
        out[((size_t)b * 512 + nb + r) * 512 + o] = v;
        s += v; q += v * v;
      }
    }
    cs[j] = s; cq[j] = q;
  }

  // per-column stats: LDS reduce (512 floats: 256 sum + 256 sumsq) -> global
  float* red = (float*)lds;
  __syncthreads();
  red[tid] = 0.f;
  __syncthreads();
  #pragma unroll
  for (int j = 0; j < 4; ++j) {
    int cl = wcol * 64 + j * 16 + fr;
    atomicAdd(&red[cl], cs[j]);
    atomicAdd(&red[256 + cl], cq[j]);
  }
  __syncthreads();
  if (tid < 256) {
    atomicAdd(&gsum[otile + tid], red[tid]);
    atomicAdd(&gsq[otile + tid],  red[256 + tid]);
  }
}

// ---------------------------------------------------------------------------
// In-place BN + mask + relu
// ---------------------------------------------------------------------------
__global__ void k_norm(const float* __restrict__ gsum, const float* __restrict__ gsq,
                       const float* __restrict__ gamma, const float* __restrict__ beta,
                       const float* __restrict__ mask, float* __restrict__ out) {
  __shared__ float sc[512], sh[512];
  for (int c = threadIdx.x; c < 512; c += blockDim.x) {
    float m   = gsum[c] * (1.f / 32768.f);
    float var = gsq[c] * (1.f / 32768.f) - m * m;
    float inv = 1.f / sqrtf(var + 1e-5f);
    float g = gamma[c] * inv;
    sc[c] = g;
    sh[c] = beta[c] - m * g;
  }
  __syncthreads();
  size_t i0 = (size_t)blockIdx.x * blockDim.x + threadIdx.x;
  size_t stride = (size_t)gridDim.x * blockDim.x;
  size_t n4 = XOUT_ELEMS / 4;
  for (size_t i = i0; i < n4; i += stride) {
    float4 p = ((const float4*)out)[i];
    int c = (int)((i * 4) & 511);
    size_t row = (i * 4) >> 9;
    float mk = mask[row];
    p.x = fmaxf((p.x * sc[c + 0] + sh[c + 0]) * mk, 0.f);
    p.y = fmaxf((p.y * sc[c + 1] + sh[c + 1]) * mk, 0.f);
    p.z = fmaxf((p.z * sc[c + 2] + sh[c + 2]) * mk, 0.f);
    p.w = fmaxf((p.w * sc[c + 3] + sh[c + 3]) * mk, 0.f);
    ((float4*)out)[i] = p;
  }
}

// ---------------------------------------------------------------------------
extern "C" void kernel_launch(void* const* d_in, const int* in_sizes, int n_in,
                              void* d_out, int out_size, void* d_ws, size_t ws_size,
                              hipStream_t stream) {
  const float* x    = (const float*)d_in[0];
  const float* adj  = (const float*)d_in[1];
  const float* gs   = (const float*)d_in[2];
  const int*   ssz  = (const int*)d_in[3];
  const float* mask = (const float*)d_in[4];
  const float* Wgfc = (const float*)d_in[5];
  const float* bgfc = (const float*)d_in[6];
  const float* Wgc  = (const float*)d_in[7];
  const float* bgc  = (const float*)d_in[8];
  const float* gn   = (const float*)d_in[9];
  const float* btn  = (const float*)d_in[10];
  const float* gg   = (const float*)d_in[11];
  const float* btg  = (const float*)d_in[12];
  float* out = (float*)d_out;

  // workspace layout (ws = 1 GiB confirmed r4/r6/r10 via poison-fill WRITE_SIZE)
  char* w = (char*)d_ws;
  float*          gt   = (float*)w;                               // 256 KiB
  unsigned short* gth  = (unsigned short*)(w + 262144);           // 128 KiB
  float*          gadd = (float*)(w + 393216);                    // 1 MiB
  int*            ns   = (int*)(w + 1441792);                     // 512 B
  float*          gsum = (float*)(w + 1442304);                   // 2 KiB
  float*          gsq  = (float*)(w + 1444352);                   // 2 KiB
  unsigned short* wT   = (unsigned short*)(w + ((size_t)34 << 20));  // 4 MiB
  unsigned short* supT = (unsigned short*)(w + ((size_t)168 << 20)); // 128 MiB

  k_decode<<<1, 64, 0, stream>>>(ssz, ns);
  k_gt<<<dim3(2, 32), 256, 0, stream>>>(gs, Wgfc, bgfc, gt, gth);
  k_gbn<<<8, 64, 0, stream>>>(gt, gg, btg, out + XOUT_ELEMS);
  hipMemsetAsync(gsum, 0, 4096, stream);

  k_cvt_w<<<dim3(32, 16, 4), 256, 0, stream>>>(Wgc, wT);
  k_gadd<<<16, 256, 0, stream>>>(gth, wT, gadd);

  k_support<<<1024, 512, 0, stream>>>(x, wT, gadd, ns, supT);
  k_xout<<<256, 512, 0, stream>>>(adj, supT, bgc, out, gsum, gsq);

  k_norm<<<2048, 256, 0, stream>>>(gsum, gsq, gn, btn, mask, out);
}